// Round 5
// baseline (177.283 us; speedup 1.0000x reference)
//
#include <hip/hip_runtime.h>
#include <math.h>

// buffer [8,64,5,64,64] fp32; Wq/Wk [8,64]; Wv/Wc [40,64]; W1 [64,40,1,1,7]; W2 [64,64,7,1,1]
// out [8,64,5,64,64] fp32

typedef __attribute__((ext_vector_type(8))) short bf16x8;
typedef __attribute__((ext_vector_type(4))) short bf16x4;
typedef __attribute__((ext_vector_type(4))) float fp32x4;
typedef __attribute__((ext_vector_type(2))) float fp32x2;
typedef __attribute__((ext_vector_type(8))) unsigned short u16x8;

// ---- workspace layout ----
// float offsets:
#define OFF_WP      0         // [og=4][c=64][l=24] proj weights fp32            (6144 f)
#define OFF_Z       29696     // [bu=8][cz=40][ar=5][h=64][w=64] fp32            (6553600 f) end 6583296
// ushort offsets (us = (unsigned short*)ws):
#define OFF_W1P_US  12288     // [wid=4][ks=9][lane=64][8] bf16 A-frag pack      (18432 us)
#define OFF_W2P_US  30720     // [wid=4][kd=7][kk=2][lane=64][8] bf16            (28672 us) end us 59392 = f 29696
#define OFF_QFH_US  13166592  // [site=512][m=320][8] bf16                       (1310720 us)
#define OFF_KFH_US  14477312  // [site][n=320][8] bf16                           (1310720 us)
#define OFF_VTH_US  15788032  // [site][j=48][n=320] bf16 (j=40 ones)            (7864320 us) end us 23652352
// total ws = 11,826,176 floats = 47.3 MB

__device__ inline unsigned short f2b(float f) {   // RNE fp32 -> bf16
    unsigned u = __builtin_bit_cast(unsigned, f);
    u = (u + 0x7fffu + ((u >> 16) & 1u)) >> 16;
    return (unsigned short)u;
}

// 16x16x16 bf16 MFMA (legacy K=16 shape, retained on gfx950).
#if __has_builtin(__builtin_amdgcn_mfma_f32_16x16x16bf16_1k)
#define MFMA16(a, b, c) __builtin_amdgcn_mfma_f32_16x16x16bf16_1k(a, b, c, 0, 0, 0)
#else
static __device__ inline fp32x4 mfma16_asm(bf16x4 a, bf16x4 b, fp32x4 c) {
    asm("v_mfma_f32_16x16x16_bf16 %0, %1, %2, %0" : "+v"(c) : "v"(a), "v"(b));
    return c;
}
#define MFMA16(a, b, c) mfma16_asm(a, b, c)
#endif

// ---------------- kernel 0: weight shuffles / MFMA A-fragment packing ----------------
__global__ void prep_weights(const float* __restrict__ Wq, const float* __restrict__ Wk,
                             const float* __restrict__ Wv, const float* __restrict__ Wc,
                             const float* __restrict__ W1, const float* __restrict__ W2,
                             float* __restrict__ ws) {
    int e = blockIdx.x * 256 + threadIdx.x;
    unsigned short* us = (unsigned short*)ws;
    if (e < 6144) {
        int og = e / 1536, r = e % 1536;
        int c = r / 24, l = r % 24;
        int o = og * 24 + l;
        float v;
        if (o < 8)       v = Wq[o * 64 + c];
        else if (o < 16) v = Wk[(o - 8) * 64 + c];
        else if (o < 56) v = Wv[(o - 16) * 64 + c];
        else             v = Wc[(o - 56) * 64 + c];
        ws[OFF_WP + e] = v;
    } else if (e < 6144 + 18432) {
        // conv1 A pack: k = kw*40 + ic (K=280 padded to 288)
        int t = e - 6144;
        int j = t & 7, lane = (t >> 3) & 63, ks = (t >> 9) % 9, wid = t / 4608;
        int oc = wid * 16 + (lane & 15);
        int k = ks * 32 + (lane >> 4) * 8 + j;
        float v = 0.f;
        if (k < 280) { int kw = k / 40, ic = k % 40; v = W1[oc * 280 + ic * 7 + kw]; }
        us[OFF_W1P_US + t] = f2b(v);
    } else if (e < 6144 + 18432 + 28672) {
        // conv2 A pack: k = kd*64 + ic (K=448 exact)
        int t = e - 6144 - 18432;
        int j = t & 7, lane = (t >> 3) & 63, kk = (t >> 9) & 1, kd = (t >> 10) % 7, wid = t / 7168;
        int oc = wid * 16 + (lane & 15);
        int ic = kk * 32 + (lane >> 4) * 8 + j;
        us[OFF_W2P_US + t] = f2b(W2[oc * 448 + ic * 7 + kd]);
    }
}

// ---------------- kernel A: q/k/v/c projections (fused og, LDS-staged x) ----------------
// grid 2560 = (bu,v,h); 256 thr = 4 waves, wave = og. x-slab staged to LDS once (float4).
// R5: accumulators paired as fp32x2 so the backend can emit v_pk_fma_f32 (VOP3P, 2 FMA/inst)
// -> VALU floor 12.8 -> 6.4 us. Per-element FMA chain order unchanged -> bit-identical.
__global__ __launch_bounds__(256) void proj_kernel(const float* __restrict__ buf,
                                                   float* __restrict__ ws) {
    __shared__ alignas(16) float xs[64 * 64];   // 16 KB
    int b = blockIdx.x;
    int h = b & 63;
    int v = (b >> 6) % 5;
    int bu = b / 320;
    int tid = threadIdx.x, wid = tid >> 6, w = tid & 63;

    // stage x[c][w] for this (bu,v,h): rows are 256B segments 80KB apart
    const float* xbase = buf + ((bu * 64) * 5 + v) * 4096 + h * 64;
    for (int e = tid; e < 1024; e += 256) {
        int c = e >> 4, wq = e & 15;
        *(float4*)&xs[c * 64 + wq * 4] = *(const float4*)&xbase[c * 20480 + wq * 4];
    }
    __syncthreads();

    int og = __builtin_amdgcn_readfirstlane(wid);
    const float* wp = ws + OFF_WP + og * 1536;

    fp32x2 acc2[12];
    #pragma unroll
    for (int l = 0; l < 12; l++) acc2[l] = (fp32x2){0.f, 0.f};
    for (int c = 0; c < 64; c++) {
        float x = xs[c * 64 + w];
        fp32x2 xv = {x, x};
        const fp32x2* wr2 = (const fp32x2*)(wp + c * 24);
        #pragma unroll
        for (int l = 0; l < 12; l++) acc2[l] += wr2[l] * xv;
    }
    float acc[24];
    #pragma unroll
    for (int l = 0; l < 12; l++) { acc[2 * l] = acc2[l][0]; acc[2 * l + 1] = acc2[l][1]; }

    int site = bu * 64 + h;
    int n = v * 64 + w;
    unsigned short* base = (unsigned short*)ws;
    unsigned short* qfh = base + OFF_QFH_US;
    unsigned short* kfh = base + OFF_KFH_US;
    unsigned short* vth = base + OFF_VTH_US;
    float* z = ws + OFF_Z;

    if (og == 0) {
        u16x8 qv, kv;
        #pragma unroll
        for (int l = 0; l < 8; l++) { qv[l] = f2b(acc[l]); kv[l] = f2b(acc[8 + l]); }
        *(u16x8*)&qfh[(site * 320 + n) * 8] = qv;
        *(u16x8*)&kfh[(site * 320 + n) * 8] = kv;
        #pragma unroll
        for (int l = 16; l < 24; l++) vth[(site * 48 + (l - 16)) * 320 + n] = f2b(acc[l]);
    } else if (og == 1) {
        #pragma unroll
        for (int l = 0; l < 24; l++) vth[(site * 48 + 8 + l) * 320 + n] = f2b(acc[l]);
    } else if (og == 2) {
        #pragma unroll
        for (int l = 0; l < 8; l++) vth[(site * 48 + 32 + l) * 320 + n] = f2b(acc[l]);
        #pragma unroll
        for (int l = 8; l < 24; l++) {
            int j2 = l - 8;
            int c8 = j2 / 5, ar = j2 % 5;
            z[((bu * 40 + c8 * 5 + v) * 5 + ar) * 4096 + h * 64 + w] = acc[l];
        }
    } else {
        #pragma unroll
        for (int l = 0; l < 24; l++) {
            int j2 = 16 + l;
            int c8 = j2 / 5, ar = j2 % 5;
            z[((bu * 40 + c8 * 5 + v) * 5 + ar) * 4096 + h * 64 + w] = acc[l];
        }
        #pragma unroll
        for (int j = 40; j < 48; j++)
            vth[(site * 48 + j) * 320 + n] = (j == 40) ? (unsigned short)0x3F80 : (unsigned short)0;
    }
}

// ---------------- kernel B: attention, register-resident P, m-chunk split ----------------
// Swapped-operand QK: sT = mfma(K, Q) puts P[m=col][n=nt*16+quad*4+r] lane-local, which IS the
// 16x16x16 fragment layout -> exp + bf16-pack feeds PV directly from registers. PV computed as
// mfma(A=V^T, B=P) so out[j=quad*4+r][m=col]: coalesced z += epilogue, uniform 1/rowsum per lane.
// m-chunk split (grid 2560): wave owns one m-tile; softmax rows (sum over n) stay in-block.
// bid = chunk*512 + site keeps all 5 chunks of a site on one XCD (512 % 8 == 0) -> V re-stage
// hits L2/L3.
__global__ __launch_bounds__(256, 2) void attn_kernel(float* __restrict__ ws) {
    __shared__ alignas(16) short vt[48 * 328];

    int bid = blockIdx.x;
    int chunk = bid >> 9;        // 0..4
    int site = bid & 511;
    int bu = site >> 6, h = site & 63;
    int tid = threadIdx.x;
    int wid = tid >> 6, lane = tid & 63;
    int col = lane & 15, quad = lane >> 4;

    const unsigned short* base = (const unsigned short*)ws;
    const unsigned short* qfh = base + OFF_QFH_US + site * 320 * 8;
    const unsigned short* kfh = base + OFF_KFH_US + site * 320 * 8;
    const unsigned short* vsrc = base + OFF_VTH_US + site * 48 * 320;
    float* z = ws + OFF_Z;

    for (int e = tid; e < 48 * 40; e += 256) {
        int row = e / 40, c8o = e % 40;
        *(u16x8*)&vt[row * 328 + c8o * 8] = *(const u16x8*)&vsrc[row * 320 + c8o * 8];
    }
    __syncthreads();

    // epilogue channel offsets: j = jt*16 + quad*4 + r -> (c8*25 + ar)*4096, c8=j/5, ar=j%5
    int off0[4], off1[4], off2[4];
    #pragma unroll
    for (int r = 0; r < 4; r++) {
        int j0 = quad * 4 + r, j1 = j0 + 16, j2 = j0 + 32;
        off0[r] = ((j0 / 5) * 25 + j0 % 5) * 4096;
        off1[r] = ((j1 / 5) * 25 + j1 % 5) * 4096;
        off2[r] = ((j2 / 5) * 25 + j2 % 5) * 4096;
    }

    int mt = chunk * 4 + wid;    // this wave's m-tile (0..19)
    int m0 = mt * 16;

    // Q^T as B operand: quad 0 holds ch 0..7 for column m = m0+col
    bf16x8 qa = (bf16x8)0;
    if (quad == 0) qa = *(const bf16x8*)&qfh[(m0 + col) * 8];

    fp32x4 acc0 = {0.f, 0.f, 0.f, 0.f}, acc1 = acc0, acc2 = acc0;

    for (int cc = 0; cc < 4; cc++) {
        fp32x4 sT[5];
        #pragma unroll
        for (int u = 0; u < 5; u++) {
            int nt = cc * 5 + u;
            bf16x8 kb = (bf16x8)0;   // A operand: K rows n = nt*16+col, ch in quad 0
            if (quad == 0) kb = *(const bf16x8*)&kfh[(nt * 16 + col) * 8];
            sT[u] = __builtin_amdgcn_mfma_f32_16x16x32_bf16(
                kb, qa, (fp32x4){0.f, 0.f, 0.f, 0.f}, 0, 0, 0);
        }
        #pragma unroll
        for (int u = 0; u < 5; u++) {
            int nt = cc * 5 + u;
            bf16x4 pa;   // P[m=col][n = nt*16 + quad*4 + r] -> K=16 fragment
            #pragma unroll
            for (int r = 0; r < 4; r++) pa[r] = (short)f2b(__expf(sT[u][r]));
            const short* vb = &vt[nt * 16 + quad * 4];
            acc0 = MFMA16(*(const bf16x4*)&vb[(col) * 328],      pa, acc0);
            acc1 = MFMA16(*(const bf16x4*)&vb[(16 + col) * 328], pa, acc1);
            acc2 = MFMA16(*(const bf16x4*)&vb[(32 + col) * 328], pa, acc2);
        }
    }

    // rowsum L[m=col] sits at j=40 -> acc2[0] on quad==2 lanes
    float L = __shfl(acc2[0], 32 + col, 64);
    float inv = 1.f / L;

    int v_idx = m0 >> 6, w0 = m0 & 63;          // uniform per m-tile
    float* zb = z + (bu * 200 + v_idx * 5) * 4096 + h * 64 + w0 + col;
    #pragma unroll
    for (int r = 0; r < 4; r++) {
        zb[off0[r]] += acc0[r] * inv;
        zb[off1[r]] += acc1[r] * inv;
        if (quad < 2) zb[off2[r]] += acc2[r] * inv;   // j = 32+quad*4+r < 40
    }
}

// ---------------- kernel C: fused conv1 (1,1,7) + conv2 (7,1,1) + ReLU, w-split ----------------
// R5: grid 1024 = (wh 2) x (bu,h 512); each block owns a 32-wide w-half. LDS 57.6 -> 29.1 KB
// (ol [5*32][72] + zl2 2x[38][40]) -> 3-4 blocks/CU vs 2, and per-block serial phase chain
// halves. Halo (+-3 in w) handled by predicated stage loads; K-order of every MFMA unchanged
// -> bit-identical. wh = bid>>9 keeps both halves of a site on one XCD (z-row overlap in L2).
__global__ __launch_bounds__(256) void conv12_mfma(float* __restrict__ ws,
                                                   float* __restrict__ out) {
    __shared__ alignas(16) unsigned short ol[160 * 72];      // 23040 B
    __shared__ alignas(16) unsigned short zl2[2][38 * 40];   // 6080 B
    int b = blockIdx.x;
    int wh = b >> 9;             // w-half 0/1
    int site = b & 511;
    int bu = site >> 6, h = site & 63;
    int whbase = wh * 32;
    int tid = threadIdx.x, wid = tid >> 6, lane = tid & 63;
    int col = lane & 15, quad = lane >> 4;
    const float* z = ws + OFF_Z;

    const unsigned short* w1p = (const unsigned short*)ws + OFF_W1P_US;
    bf16x8 a1[9];
    #pragma unroll
    for (int ks = 0; ks < 9; ks++)
        a1[ks] = *(const bf16x8*)&w1p[((wid * 9 + ks) * 64 + lane) * 8];

    // stage one ar-slab of z into zl2[bufi]: idx i (lane) <-> w' = whbase-3+i, zero outside [0,64)
    int wprime = whbase - 3 + lane;
    bool wvalid = (lane < 38) && (wprime >= 0) && (wprime < 64);
    #define STAGE_AR(ar_, bufi_)                                                          \
        {                                                                                 \
            unsigned short* zb_ = zl2[bufi_];                                             \
            for (int icq = wid; icq < 10; icq += 4) {                                     \
                ushort4 v4 = {0, 0, 0, 0};                                                \
                if (wvalid) {                                                             \
                    const float* src = z + ((bu * 40 + icq * 4) * 5 + (ar_)) * 4096 + h * 64 + wprime; \
                    v4.x = f2b(src[0]);                                                   \
                    v4.y = f2b(src[5 * 4096]);                                            \
                    v4.z = f2b(src[10 * 4096]);                                           \
                    v4.w = f2b(src[15 * 4096]);                                           \
                }                                                                         \
                if (lane < 38) *(ushort4*)&zb_[lane * 40 + icq * 4] = v4;                 \
            }                                                                             \
        }

    STAGE_AR(0, 0);
    __syncthreads();
    for (int ar = 0; ar < 5; ar++) {
        if (ar < 4) STAGE_AR(ar + 1, (ar + 1) & 1);   // prefetch into other buffer
        const unsigned short* zb = zl2[ar & 1];
        #pragma unroll
        for (int w4 = 0; w4 < 2; w4++) {
            int bb = (w4 * 16 + col) * 40;   // zl2 idx = w_local + kw (halo folded in)
            fp32x4 acc = {0.f, 0.f, 0.f, 0.f};
            #pragma unroll
            for (int ks = 0; ks < 9; ks++) {
                bf16x8 bf = *(const bf16x8*)&zb[bb + ks * 32 + quad * 8];
                acc = __builtin_amdgcn_mfma_f32_16x16x32_bf16(a1[ks], bf, acc, 0, 0, 0);
            }
            ushort4 o;
            o.x = f2b(fmaxf(acc[0], 0.f));
            o.y = f2b(fmaxf(acc[1], 0.f));
            o.z = f2b(fmaxf(acc[2], 0.f));
            o.w = f2b(fmaxf(acc[3], 0.f));
            *(ushort4*)&ol[(ar * 32 + w4 * 16 + col) * 72 + wid * 16 + quad * 4] = o;
        }
        __syncthreads();   // stage(ar+1) done; compute(ar) reads done before next overwrite
    }
    #undef STAGE_AR

    // ---- phase 2: conv2 over ar from ol ----
    const unsigned short* w2p = (const unsigned short*)ws + OFF_W2P_US;
    bf16x8 a2[7][2];
    #pragma unroll
    for (int kd = 0; kd < 7; kd++)
        #pragma unroll
        for (int kk = 0; kk < 2; kk++)
            a2[kd][kk] = *(const bf16x8*)&w2p[(((wid * 7 + kd) * 2 + kk) * 64 + lane) * 8];

    for (int nt = 0; nt < 10; nt++) {
        int ar = nt >> 1, wbase = (nt & 1) * 16;
        fp32x4 acc = {0.f, 0.f, 0.f, 0.f};
        #pragma unroll
        for (int kd = 0; kd < 7; kd++) {
            int arp = ar + kd - 3;
            if (arp >= 0 && arp < 5) {   // uniform per (nt,kd)
                int sb = (arp * 32 + wbase + col) * 72;
                #pragma unroll
                for (int kk = 0; kk < 2; kk++) {
                    bf16x8 bf = *(const bf16x8*)&ol[sb + kk * 32 + quad * 8];
                    acc = __builtin_amdgcn_mfma_f32_16x16x32_bf16(a2[kd][kk], bf, acc, 0, 0, 0);
                }
            }
        }
        int w = whbase + wbase + col;
        #pragma unroll
        for (int r = 0; r < 4; r++) {
            int oc = wid * 16 + quad * 4 + r;
            out[((bu * 64 + oc) * 5 + ar) * 4096 + h * 64 + w] = fmaxf(acc[r], 0.f);
        }
    }
}

extern "C" void kernel_launch(void* const* d_in, const int* in_sizes, int n_in,
                              void* d_out, int out_size, void* d_ws, size_t ws_size,
                              hipStream_t stream) {
    const float* buf = (const float*)d_in[0];
    const float* Wq  = (const float*)d_in[1];
    const float* Wk  = (const float*)d_in[2];
    const float* Wv  = (const float*)d_in[3];
    const float* Wc  = (const float*)d_in[4];
    const float* W1  = (const float*)d_in[5];
    const float* W2  = (const float*)d_in[6];
    float* ws  = (float*)d_ws;
    float* out = (float*)d_out;

    prep_weights<<<208, 256, 0, stream>>>(Wq, Wk, Wv, Wc, W1, W2, ws);
    proj_kernel<<<2560, 256, 0, stream>>>(buf, ws);
    attn_kernel<<<2560, 256, 0, stream>>>(ws);
    conv12_mfma<<<1024, 256, 0, stream>>>(ws, out);
}

// Round 6
// 174.380 us; speedup vs baseline: 1.0167x; 1.0167x over previous
//
#include <hip/hip_runtime.h>
#include <math.h>

// buffer [8,64,5,64,64] fp32; Wq/Wk [8,64]; Wv/Wc [40,64]; W1 [64,40,1,1,7]; W2 [64,64,7,1,1]
// out [8,64,5,64,64] fp32

typedef __attribute__((ext_vector_type(8))) short bf16x8;
typedef __attribute__((ext_vector_type(4))) short bf16x4;
typedef __attribute__((ext_vector_type(4))) float fp32x4;
typedef __attribute__((ext_vector_type(2))) float fp32x2;
typedef __attribute__((ext_vector_type(8))) unsigned short u16x8;

// ---- workspace layout ----
// float offsets:
#define OFF_WP      0         // [og=4][c=64][l=24] proj weights fp32            (6144 f)
#define OFF_Z       29696     // [bu=8][cz=40][ar=5][h=64][w=64] fp32            (6553600 f) end 6583296
// ushort offsets (us = (unsigned short*)ws):
#define OFF_W1P_US  12288     // [wid=4][ks=9][lane=64][8] bf16 A-frag pack      (18432 us)
#define OFF_W2P_US  30720     // [wid=4][kd=7][kk=2][lane=64][8] bf16            (28672 us) end us 59392 = f 29696
#define OFF_QFH_US  13166592  // [site=512][m=320][8] bf16                       (1310720 us)
#define OFF_KFH_US  14477312  // [site][n=320][8] bf16                           (1310720 us)
#define OFF_VTH_US  15788032  // [site][j=48][n=320] bf16 (j=40 ones)            (7864320 us) end us 23652352
// total ws = 11,826,176 floats = 47.3 MB

__device__ inline unsigned short f2b(float f) {   // RNE fp32 -> bf16
    unsigned u = __builtin_bit_cast(unsigned, f);
    u = (u + 0x7fffu + ((u >> 16) & 1u)) >> 16;
    return (unsigned short)u;
}

// 16x16x16 bf16 MFMA (legacy K=16 shape, retained on gfx950).
#if __has_builtin(__builtin_amdgcn_mfma_f32_16x16x16bf16_1k)
#define MFMA16(a, b, c) __builtin_amdgcn_mfma_f32_16x16x16bf16_1k(a, b, c, 0, 0, 0)
#else
static __device__ inline fp32x4 mfma16_asm(bf16x4 a, bf16x4 b, fp32x4 c) {
    asm("v_mfma_f32_16x16x16_bf16 %0, %1, %2, %0" : "+v"(c) : "v"(a), "v"(b));
    return c;
}
#define MFMA16(a, b, c) mfma16_asm(a, b, c)
#endif

// ---------------- kernel 0: weight shuffles / MFMA A-fragment packing ----------------
__global__ void prep_weights(const float* __restrict__ Wq, const float* __restrict__ Wk,
                             const float* __restrict__ Wv, const float* __restrict__ Wc,
                             const float* __restrict__ W1, const float* __restrict__ W2,
                             float* __restrict__ ws) {
    int e = blockIdx.x * 256 + threadIdx.x;
    unsigned short* us = (unsigned short*)ws;
    if (e < 6144) {
        int og = e / 1536, r = e % 1536;
        int c = r / 24, l = r % 24;
        int o = og * 24 + l;
        float v;
        if (o < 8)       v = Wq[o * 64 + c];
        else if (o < 16) v = Wk[(o - 8) * 64 + c];
        else if (o < 56) v = Wv[(o - 16) * 64 + c];
        else             v = Wc[(o - 56) * 64 + c];
        ws[OFF_WP + e] = v;
    } else if (e < 6144 + 18432) {
        // conv1 A pack: k = kw*40 + ic (K=280 padded to 288)
        int t = e - 6144;
        int j = t & 7, lane = (t >> 3) & 63, ks = (t >> 9) % 9, wid = t / 4608;
        int oc = wid * 16 + (lane & 15);
        int k = ks * 32 + (lane >> 4) * 8 + j;
        float v = 0.f;
        if (k < 280) { int kw = k / 40, ic = k % 40; v = W1[oc * 280 + ic * 7 + kw]; }
        us[OFF_W1P_US + t] = f2b(v);
    } else if (e < 6144 + 18432 + 28672) {
        // conv2 A pack: k = kd*64 + ic (K=448 exact)
        int t = e - 6144 - 18432;
        int j = t & 7, lane = (t >> 3) & 63, kk = (t >> 9) & 1, kd = (t >> 10) % 7, wid = t / 7168;
        int oc = wid * 16 + (lane & 15);
        int ic = kk * 32 + (lane >> 4) * 8 + j;
        us[OFF_W2P_US + t] = f2b(W2[oc * 448 + ic * 7 + kd]);
    }
}

// ---------------- kernel A: q/k/v/c projections (fused og, LDS-staged x) ----------------
// grid 2560 = (bu,v,h); 256 thr = 4 waves, wave = og. x-slab staged to LDS once (float4).
// Accumulators paired as fp32x2 so the backend can emit v_pk_fma_f32 (VOP3P, 2 FMA/inst).
// Per-element FMA chain order unchanged -> bit-identical.
__global__ __launch_bounds__(256) void proj_kernel(const float* __restrict__ buf,
                                                   float* __restrict__ ws) {
    __shared__ alignas(16) float xs[64 * 64];   // 16 KB
    int b = blockIdx.x;
    int h = b & 63;
    int v = (b >> 6) % 5;
    int bu = b / 320;
    int tid = threadIdx.x, wid = tid >> 6, w = tid & 63;

    // stage x[c][w] for this (bu,v,h): rows are 256B segments 80KB apart
    const float* xbase = buf + ((bu * 64) * 5 + v) * 4096 + h * 64;
    for (int e = tid; e < 1024; e += 256) {
        int c = e >> 4, wq = e & 15;
        *(float4*)&xs[c * 64 + wq * 4] = *(const float4*)&xbase[c * 20480 + wq * 4];
    }
    __syncthreads();

    int og = __builtin_amdgcn_readfirstlane(wid);
    const float* wp = ws + OFF_WP + og * 1536;

    fp32x2 acc2[12];
    #pragma unroll
    for (int l = 0; l < 12; l++) acc2[l] = (fp32x2){0.f, 0.f};
    for (int c = 0; c < 64; c++) {
        float x = xs[c * 64 + w];
        fp32x2 xv = {x, x};
        const fp32x2* wr2 = (const fp32x2*)(wp + c * 24);
        #pragma unroll
        for (int l = 0; l < 12; l++) acc2[l] += wr2[l] * xv;
    }
    float acc[24];
    #pragma unroll
    for (int l = 0; l < 12; l++) { acc[2 * l] = acc2[l][0]; acc[2 * l + 1] = acc2[l][1]; }

    int site = bu * 64 + h;
    int n = v * 64 + w;
    unsigned short* base = (unsigned short*)ws;
    unsigned short* qfh = base + OFF_QFH_US;
    unsigned short* kfh = base + OFF_KFH_US;
    unsigned short* vth = base + OFF_VTH_US;
    float* z = ws + OFF_Z;

    if (og == 0) {
        u16x8 qv, kv;
        #pragma unroll
        for (int l = 0; l < 8; l++) { qv[l] = f2b(acc[l]); kv[l] = f2b(acc[8 + l]); }
        *(u16x8*)&qfh[(site * 320 + n) * 8] = qv;
        *(u16x8*)&kfh[(site * 320 + n) * 8] = kv;
        #pragma unroll
        for (int l = 16; l < 24; l++) vth[(site * 48 + (l - 16)) * 320 + n] = f2b(acc[l]);
    } else if (og == 1) {
        #pragma unroll
        for (int l = 0; l < 24; l++) vth[(site * 48 + 8 + l) * 320 + n] = f2b(acc[l]);
    } else if (og == 2) {
        #pragma unroll
        for (int l = 0; l < 8; l++) vth[(site * 48 + 32 + l) * 320 + n] = f2b(acc[l]);
        #pragma unroll
        for (int l = 8; l < 24; l++) {
            int j2 = l - 8;
            int c8 = j2 / 5, ar = j2 % 5;
            z[((bu * 40 + c8 * 5 + v) * 5 + ar) * 4096 + h * 64 + w] = acc[l];
        }
    } else {
        #pragma unroll
        for (int l = 0; l < 24; l++) {
            int j2 = 16 + l;
            int c8 = j2 / 5, ar = j2 % 5;
            z[((bu * 40 + c8 * 5 + v) * 5 + ar) * 4096 + h * 64 + w] = acc[l];
        }
        #pragma unroll
        for (int j = 40; j < 48; j++)
            vth[(site * 48 + j) * 320 + n] = (j == 40) ? (unsigned short)0x3F80 : (unsigned short)0;
    }
}

// ---------------- kernel B: attention, register-resident P, m-chunk split ----------------
// Swapped-operand QK: sT = mfma(K, Q) puts P[m=col][n=nt*16+quad*4+r] lane-local, which IS the
// 16x16x16 fragment layout -> exp + bf16-pack feeds PV directly from registers. PV computed as
// mfma(A=V^T, B=P) so out[j=quad*4+r][m=col]: coalesced z += epilogue, uniform 1/rowsum per lane.
// m-chunk split (grid 2560): wave owns one m-tile; softmax rows (sum over n) stay in-block.
// bid = chunk*512 + site keeps all 5 chunks of a site on one XCD (512 % 8 == 0) -> V re-stage
// hits L2/L3.
__global__ __launch_bounds__(256, 2) void attn_kernel(float* __restrict__ ws) {
    __shared__ alignas(16) short vt[48 * 328];

    int bid = blockIdx.x;
    int chunk = bid >> 9;        // 0..4
    int site = bid & 511;
    int bu = site >> 6, h = site & 63;
    int tid = threadIdx.x;
    int wid = tid >> 6, lane = tid & 63;
    int col = lane & 15, quad = lane >> 4;

    const unsigned short* base = (const unsigned short*)ws;
    const unsigned short* qfh = base + OFF_QFH_US + site * 320 * 8;
    const unsigned short* kfh = base + OFF_KFH_US + site * 320 * 8;
    const unsigned short* vsrc = base + OFF_VTH_US + site * 48 * 320;
    float* z = ws + OFF_Z;

    for (int e = tid; e < 48 * 40; e += 256) {
        int row = e / 40, c8o = e % 40;
        *(u16x8*)&vt[row * 328 + c8o * 8] = *(const u16x8*)&vsrc[row * 320 + c8o * 8];
    }
    __syncthreads();

    // epilogue channel offsets: j = jt*16 + quad*4 + r -> (c8*25 + ar)*4096, c8=j/5, ar=j%5
    int off0[4], off1[4], off2[4];
    #pragma unroll
    for (int r = 0; r < 4; r++) {
        int j0 = quad * 4 + r, j1 = j0 + 16, j2 = j0 + 32;
        off0[r] = ((j0 / 5) * 25 + j0 % 5) * 4096;
        off1[r] = ((j1 / 5) * 25 + j1 % 5) * 4096;
        off2[r] = ((j2 / 5) * 25 + j2 % 5) * 4096;
    }

    int mt = chunk * 4 + wid;    // this wave's m-tile (0..19)
    int m0 = mt * 16;

    // Q^T as B operand: quad 0 holds ch 0..7 for column m = m0+col
    bf16x8 qa = (bf16x8)0;
    if (quad == 0) qa = *(const bf16x8*)&qfh[(m0 + col) * 8];

    fp32x4 acc0 = {0.f, 0.f, 0.f, 0.f}, acc1 = acc0, acc2 = acc0;

    for (int cc = 0; cc < 4; cc++) {
        fp32x4 sT[5];
        #pragma unroll
        for (int u = 0; u < 5; u++) {
            int nt = cc * 5 + u;
            bf16x8 kb = (bf16x8)0;   // A operand: K rows n = nt*16+col, ch in quad 0
            if (quad == 0) kb = *(const bf16x8*)&kfh[(nt * 16 + col) * 8];
            sT[u] = __builtin_amdgcn_mfma_f32_16x16x32_bf16(
                kb, qa, (fp32x4){0.f, 0.f, 0.f, 0.f}, 0, 0, 0);
        }
        #pragma unroll
        for (int u = 0; u < 5; u++) {
            int nt = cc * 5 + u;
            bf16x4 pa;   // P[m=col][n = nt*16 + quad*4 + r] -> K=16 fragment
            #pragma unroll
            for (int r = 0; r < 4; r++) pa[r] = (short)f2b(__expf(sT[u][r]));
            const short* vb = &vt[nt * 16 + quad * 4];
            acc0 = MFMA16(*(const bf16x4*)&vb[(col) * 328],      pa, acc0);
            acc1 = MFMA16(*(const bf16x4*)&vb[(16 + col) * 328], pa, acc1);
            acc2 = MFMA16(*(const bf16x4*)&vb[(32 + col) * 328], pa, acc2);
        }
    }

    // rowsum L[m=col] sits at j=40 -> acc2[0] on quad==2 lanes
    float L = __shfl(acc2[0], 32 + col, 64);
    float inv = 1.f / L;

    int v_idx = m0 >> 6, w0 = m0 & 63;          // uniform per m-tile
    float* zb = z + (bu * 200 + v_idx * 5) * 4096 + h * 64 + w0 + col;
    #pragma unroll
    for (int r = 0; r < 4; r++) {
        zb[off0[r]] += acc0[r] * inv;
        zb[off1[r]] += acc1[r] * inv;
        if (quad < 2) zb[off2[r]] += acc2[r] * inv;   // j = 32+quad*4+r < 40
    }
}

// ---------------- kernel C: fused conv1 (1,1,7) + conv2 (7,1,1) + ReLU via bf16 MFMA ----------------
// R4 structure (R5's w-split reverted: VGPR-bound at ~2-3 waves/SIMD from 23 A-fragments in
// registers, so halving LDS bought no occupancy while doubling per-block fixed costs).
// grid 512 = (bu,h); 256 thr. Phase 1 (conv1): per-ar z slab [wp=w+kw (72)][ic 40] bf16,
// double-buffered; conv1 bf16 results written straight to the ol slab. Phase 2 (conv2):
// reads ol from LDS. LDS 46080+11520 = 57.6 KB.
__global__ __launch_bounds__(256) void conv12_mfma(float* __restrict__ ws,
                                                   float* __restrict__ out) {
    __shared__ alignas(16) unsigned short ol[320 * 72];      // 46080 B
    __shared__ alignas(16) unsigned short zl2[2][72 * 40];   // 11520 B
    int b = blockIdx.x;
    int bu = b >> 6, h = b & 63;
    int tid = threadIdx.x, wid = tid >> 6, lane = tid & 63;
    int col = lane & 15, quad = lane >> 4;
    const float* z = ws + OFF_Z;

    const unsigned short* w1p = (const unsigned short*)ws + OFF_W1P_US;
    bf16x8 a1[9];
    #pragma unroll
    for (int ks = 0; ks < 9; ks++)
        a1[ks] = *(const bf16x8*)&w1p[((wid * 9 + ks) * 64 + lane) * 8];

    // stage one ar-slab of z into zl2[bufi]: halo zeros wp in {0,1,2,67..71}, interior wp=3+w
    #define STAGE_AR(ar_, bufi_)                                                          \
        {                                                                                 \
            unsigned short* zb_ = zl2[bufi_];                                             \
            if (tid < 160) {                                                              \
                int wpi = tid / 20, icd = tid % 20;                                       \
                int wp = wpi < 3 ? wpi : wpi + 64;                                        \
                ((unsigned*)zb_)[wp * 20 + icd] = 0u;                                     \
            }                                                                             \
            for (int icq = wid; icq < 10; icq += 4) {                                     \
                const float* src = z + ((bu * 40 + icq * 4) * 5 + (ar_)) * 4096 + h * 64 + lane; \
                ushort4 v4;                                                               \
                v4.x = f2b(src[0]);                                                       \
                v4.y = f2b(src[5 * 4096]);                                                \
                v4.z = f2b(src[10 * 4096]);                                               \
                v4.w = f2b(src[15 * 4096]);                                               \
                *(ushort4*)&zb_[(3 + lane) * 40 + icq * 4] = v4;                          \
            }                                                                             \
        }

    STAGE_AR(0, 0);
    __syncthreads();
    for (int ar = 0; ar < 5; ar++) {
        if (ar < 4) STAGE_AR(ar + 1, (ar + 1) & 1);   // prefetch into other buffer
        const unsigned short* zb = zl2[ar & 1];
        #pragma unroll
        for (int w4 = 0; w4 < 4; w4++) {
            int bb = (w4 * 16 + col) * 40;   // wp = w + kw, zl[wp] = z[wp-3]
            fp32x4 acc = {0.f, 0.f, 0.f, 0.f};
            #pragma unroll
            for (int ks = 0; ks < 9; ks++) {
                bf16x8 bf = *(const bf16x8*)&zb[bb + ks * 32 + quad * 8];
                acc = __builtin_amdgcn_mfma_f32_16x16x32_bf16(a1[ks], bf, acc, 0, 0, 0);
            }
            ushort4 o;
            o.x = f2b(fmaxf(acc[0], 0.f));
            o.y = f2b(fmaxf(acc[1], 0.f));
            o.z = f2b(fmaxf(acc[2], 0.f));
            o.w = f2b(fmaxf(acc[3], 0.f));
            *(ushort4*)&ol[(ar * 64 + w4 * 16 + col) * 72 + wid * 16 + quad * 4] = o;
        }
        __syncthreads();   // stage(ar+1) done; compute(ar) reads done before next overwrite
    }
    #undef STAGE_AR

    // ---- phase 2: conv2 over ar from ol ----
    const unsigned short* w2p = (const unsigned short*)ws + OFF_W2P_US;
    bf16x8 a2[7][2];
    #pragma unroll
    for (int kd = 0; kd < 7; kd++)
        #pragma unroll
        for (int kk = 0; kk < 2; kk++)
            a2[kd][kk] = *(const bf16x8*)&w2p[(((wid * 7 + kd) * 2 + kk) * 64 + lane) * 8];

    for (int nt = 0; nt < 20; nt++) {
        int ar = nt >> 2, wbase = (nt & 3) * 16;
        fp32x4 acc = {0.f, 0.f, 0.f, 0.f};
        #pragma unroll
        for (int kd = 0; kd < 7; kd++) {
            int arp = ar + kd - 3;
            if (arp >= 0 && arp < 5) {   // uniform per (nt,kd)
                int sb = (arp * 64 + wbase + col) * 72;
                #pragma unroll
                for (int kk = 0; kk < 2; kk++) {
                    bf16x8 bf = *(const bf16x8*)&ol[sb + kk * 32 + quad * 8];
                    acc = __builtin_amdgcn_mfma_f32_16x16x32_bf16(a2[kd][kk], bf, acc, 0, 0, 0);
                }
            }
        }
        int w = wbase + col;
        #pragma unroll
        for (int r = 0; r < 4; r++) {
            int oc = wid * 16 + quad * 4 + r;
            out[((bu * 64 + oc) * 5 + ar) * 4096 + h * 64 + w] = fmaxf(acc[r], 0.f);
        }
    }
}

extern "C" void kernel_launch(void* const* d_in, const int* in_sizes, int n_in,
                              void* d_out, int out_size, void* d_ws, size_t ws_size,
                              hipStream_t stream) {
    const float* buf = (const float*)d_in[0];
    const float* Wq  = (const float*)d_in[1];
    const float* Wk  = (const float*)d_in[2];
    const float* Wv  = (const float*)d_in[3];
    const float* Wc  = (const float*)d_in[4];
    const float* W1  = (const float*)d_in[5];
    const float* W2  = (const float*)d_in[6];
    float* ws  = (float*)d_ws;
    float* out = (float*)d_out;

    prep_weights<<<208, 256, 0, stream>>>(Wq, Wk, Wv, Wc, W1, W2, ws);
    proj_kernel<<<2560, 256, 0, stream>>>(buf, ws);
    attn_kernel<<<2560, 256, 0, stream>>>(ws);
    conv12_mfma<<<512, 256, 0, stream>>>(ws, out);
}

// Round 7
// 166.772 us; speedup vs baseline: 1.0630x; 1.0456x over previous
//
#include <hip/hip_runtime.h>
#include <math.h>

// buffer [8,64,5,64,64] fp32; Wq/Wk [8,64]; Wv/Wc [40,64]; W1 [64,40,1,1,7]; W2 [64,64,7,1,1]
// out [8,64,5,64,64] fp32

typedef __attribute__((ext_vector_type(8))) short bf16x8;
typedef __attribute__((ext_vector_type(4))) short bf16x4;
typedef __attribute__((ext_vector_type(4))) float fp32x4;
typedef __attribute__((ext_vector_type(8))) unsigned short u16x8;

// ---- workspace layout ----
// float offsets:
#define OFF_WP      0         // [og=4][c=64][l=24] proj weights fp32            (6144 f)
#define OFF_Z       29696     // [bu=8][cz=40][ar=5][h=64][w=64] fp32            (6553600 f) end 6583296
// ushort offsets (us = (unsigned short*)ws):
#define OFF_W1P_US  12288     // [wid=4][ks=9][lane=64][8] bf16 A-frag pack      (18432 us)
#define OFF_W2P_US  30720     // [wid=4][kd=7][kk=2][lane=64][8] bf16            (28672 us) end us 59392 = f 29696
#define OFF_QFH_US  13166592  // [site=512][m=320][8] bf16                       (1310720 us)
#define OFF_KFH_US  14477312  // [site][n=320][8] bf16                           (1310720 us)
#define OFF_VTH_US  15788032  // [site][j=48][n=320] bf16 (j=40 ones)            (7864320 us) end us 23652352
// total ws = 11,826,176 floats = 47.3 MB

__device__ inline unsigned short f2b(float f) {   // RNE fp32 -> bf16
    unsigned u = __builtin_bit_cast(unsigned, f);
    u = (u + 0x7fffu + ((u >> 16) & 1u)) >> 16;
    return (unsigned short)u;
}

// 16x16x16 bf16 MFMA (legacy K=16 shape, retained on gfx950).
#if __has_builtin(__builtin_amdgcn_mfma_f32_16x16x16bf16_1k)
#define MFMA16(a, b, c) __builtin_amdgcn_mfma_f32_16x16x16bf16_1k(a, b, c, 0, 0, 0)
#else
static __device__ inline fp32x4 mfma16_asm(bf16x4 a, bf16x4 b, fp32x4 c) {
    asm("v_mfma_f32_16x16x16_bf16 %0, %1, %2, %0" : "+v"(c) : "v"(a), "v"(b));
    return c;
}
#define MFMA16(a, b, c) mfma16_asm(a, b, c)
#endif

// ---------------- kernel 0: weight shuffles / MFMA A-fragment packing ----------------
__global__ void prep_weights(const float* __restrict__ Wq, const float* __restrict__ Wk,
                             const float* __restrict__ Wv, const float* __restrict__ Wc,
                             const float* __restrict__ W1, const float* __restrict__ W2,
                             float* __restrict__ ws) {
    int e = blockIdx.x * 256 + threadIdx.x;
    unsigned short* us = (unsigned short*)ws;
    if (e < 6144) {
        int og = e / 1536, r = e % 1536;
        int c = r / 24, l = r % 24;
        int o = og * 24 + l;
        float v;
        if (o < 8)       v = Wq[o * 64 + c];
        else if (o < 16) v = Wk[(o - 8) * 64 + c];
        else if (o < 56) v = Wv[(o - 16) * 64 + c];
        else             v = Wc[(o - 56) * 64 + c];
        ws[OFF_WP + e] = v;
    } else if (e < 6144 + 18432) {
        // conv1 A pack: k = kw*40 + ic (K=280 padded to 288)
        int t = e - 6144;
        int j = t & 7, lane = (t >> 3) & 63, ks = (t >> 9) % 9, wid = t / 4608;
        int oc = wid * 16 + (lane & 15);
        int k = ks * 32 + (lane >> 4) * 8 + j;
        float v = 0.f;
        if (k < 280) { int kw = k / 40, ic = k % 40; v = W1[oc * 280 + ic * 7 + kw]; }
        us[OFF_W1P_US + t] = f2b(v);
    } else if (e < 6144 + 18432 + 28672) {
        // conv2 A pack: k = kd*64 + ic (K=448 exact)
        int t = e - 6144 - 18432;
        int j = t & 7, lane = (t >> 3) & 63, kk = (t >> 9) & 1, kd = (t >> 10) % 7, wid = t / 7168;
        int oc = wid * 16 + (lane & 15);
        int ic = kk * 32 + (lane >> 4) * 8 + j;
        us[OFF_W2P_US + t] = f2b(W2[oc * 448 + ic * 7 + kd]);
    }
}

// ---------------- kernel A: q/k/v/c projections (fused og, LDS-staged x) ----------------
// grid 2560 = (bu,v,h); 256 thr = 4 waves, wave = og. x-slab [c=64][w=64] fp32 staged to
// LDS once (coalesced float4). readfirstlane(og) keeps weight reads scalar.
// R6 post-mortem: fp32x2 pk-FMA was +3 us (proj is not VALU-issue-bound) -> reverted to R4 form.
__global__ __launch_bounds__(256) void proj_kernel(const float* __restrict__ buf,
                                                   float* __restrict__ ws) {
    __shared__ alignas(16) float xs[64 * 64];   // 16 KB
    int b = blockIdx.x;
    int h = b & 63;
    int v = (b >> 6) % 5;
    int bu = b / 320;
    int tid = threadIdx.x, wid = tid >> 6, w = tid & 63;

    // stage x[c][w] for this (bu,v,h): rows are 256B segments 80KB apart
    const float* xbase = buf + ((bu * 64) * 5 + v) * 4096 + h * 64;
    for (int e = tid; e < 1024; e += 256) {
        int c = e >> 4, wq = e & 15;
        *(float4*)&xs[c * 64 + wq * 4] = *(const float4*)&xbase[c * 20480 + wq * 4];
    }
    __syncthreads();

    int og = __builtin_amdgcn_readfirstlane(wid);
    const float* wp = ws + OFF_WP + og * 1536;

    float acc[24];
    #pragma unroll
    for (int l = 0; l < 24; l++) acc[l] = 0.f;
    for (int c = 0; c < 64; c++) {
        float x = xs[c * 64 + w];
        const float* wr = wp + c * 24;
        #pragma unroll
        for (int l = 0; l < 24; l++) acc[l] += wr[l] * x;
    }

    int site = bu * 64 + h;
    int n = v * 64 + w;
    unsigned short* base = (unsigned short*)ws;
    unsigned short* qfh = base + OFF_QFH_US;
    unsigned short* kfh = base + OFF_KFH_US;
    unsigned short* vth = base + OFF_VTH_US;
    float* z = ws + OFF_Z;

    if (og == 0) {
        u16x8 qv, kv;
        #pragma unroll
        for (int l = 0; l < 8; l++) { qv[l] = f2b(acc[l]); kv[l] = f2b(acc[8 + l]); }
        *(u16x8*)&qfh[(site * 320 + n) * 8] = qv;
        *(u16x8*)&kfh[(site * 320 + n) * 8] = kv;
        #pragma unroll
        for (int l = 16; l < 24; l++) vth[(site * 48 + (l - 16)) * 320 + n] = f2b(acc[l]);
    } else if (og == 1) {
        #pragma unroll
        for (int l = 0; l < 24; l++) vth[(site * 48 + 8 + l) * 320 + n] = f2b(acc[l]);
    } else if (og == 2) {
        #pragma unroll
        for (int l = 0; l < 8; l++) vth[(site * 48 + 32 + l) * 320 + n] = f2b(acc[l]);
        #pragma unroll
        for (int l = 8; l < 24; l++) {
            int j2 = l - 8;
            int c8 = j2 / 5, ar = j2 % 5;
            z[((bu * 40 + c8 * 5 + v) * 5 + ar) * 4096 + h * 64 + w] = acc[l];
        }
    } else {
        #pragma unroll
        for (int l = 0; l < 24; l++) {
            int j2 = 16 + l;
            int c8 = j2 / 5, ar = j2 % 5;
            z[((bu * 40 + c8 * 5 + v) * 5 + ar) * 4096 + h * 64 + w] = acc[l];
        }
        #pragma unroll
        for (int j = 40; j < 48; j++)
            vth[(site * 48 + j) * 320 + n] = (j == 40) ? (unsigned short)0x3F80 : (unsigned short)0;
    }
}

// ---------------- kernel B: attention, register-resident P, m-chunk split ----------------
// Swapped-operand QK: sT = mfma(K, Q) puts P[m=col][n=nt*16+quad*4+r] lane-local, which IS the
// 16x16x16 fragment layout -> exp + bf16-pack feeds PV directly from registers. PV computed as
// mfma(A=V^T, B=P) so out[j=quad*4+r][m=col]: coalesced z += epilogue, uniform 1/rowsum per lane.
// m-chunk split (grid 2560): wave owns one m-tile; softmax rows (sum over n) stay in-block.
// bid = chunk*512 + site keeps all 5 chunks of a site on one XCD (512 % 8 == 0).
// R7: prefetch the z-RMW reads right after the barrier -- the 11 dependent loads' latency
// (~500-900 cyc) was exposed as a serial per-wave tail after all compute; issuing them before
// the QK loop hides them under the ~2-3K-cycle MFMA/softmax phase. Bit-identical (same load,
// same add; each z location touched by exactly one wave). +~11 VGPR, still <=128.
__global__ __launch_bounds__(256, 2) void attn_kernel(float* __restrict__ ws) {
    __shared__ alignas(16) short vt[48 * 328];

    int bid = blockIdx.x;
    int chunk = bid >> 9;        // 0..4
    int site = bid & 511;
    int bu = site >> 6, h = site & 63;
    int tid = threadIdx.x;
    int wid = tid >> 6, lane = tid & 63;
    int col = lane & 15, quad = lane >> 4;

    const unsigned short* base = (const unsigned short*)ws;
    const unsigned short* qfh = base + OFF_QFH_US + site * 320 * 8;
    const unsigned short* kfh = base + OFF_KFH_US + site * 320 * 8;
    const unsigned short* vsrc = base + OFF_VTH_US + site * 48 * 320;
    float* z = ws + OFF_Z;

    for (int e = tid; e < 48 * 40; e += 256) {
        int row = e / 40, c8o = e % 40;
        *(u16x8*)&vt[row * 328 + c8o * 8] = *(const u16x8*)&vsrc[row * 320 + c8o * 8];
    }
    __syncthreads();

    // epilogue channel offsets: j = jt*16 + quad*4 + r -> (c8*25 + ar)*4096, c8=j/5, ar=j%5
    int off0[4], off1[4], off2[4];
    #pragma unroll
    for (int r = 0; r < 4; r++) {
        int j0 = quad * 4 + r, j1 = j0 + 16, j2 = j0 + 32;
        off0[r] = ((j0 / 5) * 25 + j0 % 5) * 4096;
        off1[r] = ((j1 / 5) * 25 + j1 % 5) * 4096;
        off2[r] = ((j2 / 5) * 25 + j2 % 5) * 4096;
    }

    int mt = chunk * 4 + wid;    // this wave's m-tile (0..19)
    int m0 = mt * 16;

    // z-prefetch: addresses known now; loads drain while QK/softmax/PV runs
    int v_idx = m0 >> 6, w0 = m0 & 63;          // uniform per m-tile
    float* zb = z + (bu * 200 + v_idx * 5) * 4096 + h * 64 + w0 + col;
    float zold0[4], zold1[4], zold2[4];
    #pragma unroll
    for (int r = 0; r < 4; r++) {
        zold0[r] = zb[off0[r]];
        zold1[r] = zb[off1[r]];
        zold2[r] = (quad < 2) ? zb[off2[r]] : 0.f;
    }

    // Q^T as B operand: quad 0 holds ch 0..7 for column m = m0+col
    bf16x8 qa = (bf16x8)0;
    if (quad == 0) qa = *(const bf16x8*)&qfh[(m0 + col) * 8];

    fp32x4 acc0 = {0.f, 0.f, 0.f, 0.f}, acc1 = acc0, acc2 = acc0;

    for (int cc = 0; cc < 4; cc++) {
        fp32x4 sT[5];
        #pragma unroll
        for (int u = 0; u < 5; u++) {
            int nt = cc * 5 + u;
            bf16x8 kb = (bf16x8)0;   // A operand: K rows n = nt*16+col, ch in quad 0
            if (quad == 0) kb = *(const bf16x8*)&kfh[(nt * 16 + col) * 8];
            sT[u] = __builtin_amdgcn_mfma_f32_16x16x32_bf16(
                kb, qa, (fp32x4){0.f, 0.f, 0.f, 0.f}, 0, 0, 0);
        }
        #pragma unroll
        for (int u = 0; u < 5; u++) {
            int nt = cc * 5 + u;
            bf16x4 pa;   // P[m=col][n = nt*16 + quad*4 + r] -> K=16 fragment
            #pragma unroll
            for (int r = 0; r < 4; r++) pa[r] = (short)f2b(__expf(sT[u][r]));
            const short* vb = &vt[nt * 16 + quad * 4];
            acc0 = MFMA16(*(const bf16x4*)&vb[(col) * 328],      pa, acc0);
            acc1 = MFMA16(*(const bf16x4*)&vb[(16 + col) * 328], pa, acc1);
            acc2 = MFMA16(*(const bf16x4*)&vb[(32 + col) * 328], pa, acc2);
        }
    }

    // rowsum L[m=col] sits at j=40 -> acc2[0] on quad==2 lanes
    float L = __shfl(acc2[0], 32 + col, 64);
    float inv = 1.f / L;

    #pragma unroll
    for (int r = 0; r < 4; r++) {
        zb[off0[r]] = zold0[r] + acc0[r] * inv;
        zb[off1[r]] = zold1[r] + acc1[r] * inv;
        if (quad < 2) zb[off2[r]] = zold2[r] + acc2[r] * inv;   // j = 32+quad*4+r < 40
    }
}

// ---------------- kernel C: fused conv1 (1,1,7) + conv2 (7,1,1) + ReLU via bf16 MFMA ----------------
// R4 structure. grid 512 = (bu,h); 256 thr. Phase 1 (conv1): per-ar z slab [wp=w+kw (72)][ic 40]
// bf16, double-buffered; conv1 bf16 results written straight to the ol slab. Phase 2 (conv2):
// reads ol from LDS. LDS 46080+11520 = 57.6 KB.
__global__ __launch_bounds__(256) void conv12_mfma(float* __restrict__ ws,
                                                   float* __restrict__ out) {
    __shared__ alignas(16) unsigned short ol[320 * 72];      // 46080 B
    __shared__ alignas(16) unsigned short zl2[2][72 * 40];   // 11520 B
    int b = blockIdx.x;
    int bu = b >> 6, h = b & 63;
    int tid = threadIdx.x, wid = tid >> 6, lane = tid & 63;
    int col = lane & 15, quad = lane >> 4;
    const float* z = ws + OFF_Z;

    const unsigned short* w1p = (const unsigned short*)ws + OFF_W1P_US;
    bf16x8 a1[9];
    #pragma unroll
    for (int ks = 0; ks < 9; ks++)
        a1[ks] = *(const bf16x8*)&w1p[((wid * 9 + ks) * 64 + lane) * 8];

    // stage one ar-slab of z into zl2[bufi]: halo zeros wp in {0,1,2,67..71}, interior wp=3+w
    #define STAGE_AR(ar_, bufi_)                                                          \
        {                                                                                 \
            unsigned short* zb_ = zl2[bufi_];                                             \
            if (tid < 160) {                                                              \
                int wpi = tid / 20, icd = tid % 20;                                       \
                int wp = wpi < 3 ? wpi : wpi + 64;                                        \
                ((unsigned*)zb_)[wp * 20 + icd] = 0u;                                     \
            }                                                                             \
            for (int icq = wid; icq < 10; icq += 4) {                                     \
                const float* src = z + ((bu * 40 + icq * 4) * 5 + (ar_)) * 4096 + h * 64 + lane; \
                ushort4 v4;                                                               \
                v4.x = f2b(src[0]);                                                       \
                v4.y = f2b(src[5 * 4096]);                                                \
                v4.z = f2b(src[10 * 4096]);                                               \
                v4.w = f2b(src[15 * 4096]);                                               \
                *(ushort4*)&zb_[(3 + lane) * 40 + icq * 4] = v4;                          \
            }                                                                             \
        }

    STAGE_AR(0, 0);
    __syncthreads();
    for (int ar = 0; ar < 5; ar++) {
        if (ar < 4) STAGE_AR(ar + 1, (ar + 1) & 1);   // prefetch into other buffer
        const unsigned short* zb = zl2[ar & 1];
        #pragma unroll
        for (int w4 = 0; w4 < 4; w4++) {
            int bb = (w4 * 16 + col) * 40;   // wp = w + kw, zl[wp] = z[wp-3]
            fp32x4 acc = {0.f, 0.f, 0.f, 0.f};
            #pragma unroll
            for (int ks = 0; ks < 9; ks++) {
                bf16x8 bf = *(const bf16x8*)&zb[bb + ks * 32 + quad * 8];
                acc = __builtin_amdgcn_mfma_f32_16x16x32_bf16(a1[ks], bf, acc, 0, 0, 0);
            }
            ushort4 o;
            o.x = f2b(fmaxf(acc[0], 0.f));
            o.y = f2b(fmaxf(acc[1], 0.f));
            o.z = f2b(fmaxf(acc[2], 0.f));
            o.w = f2b(fmaxf(acc[3], 0.f));
            *(ushort4*)&ol[(ar * 64 + w4 * 16 + col) * 72 + wid * 16 + quad * 4] = o;
        }
        __syncthreads();   // stage(ar+1) done; compute(ar) reads done before next overwrite
    }
    #undef STAGE_AR

    // ---- phase 2: conv2 over ar from ol ----
    const unsigned short* w2p = (const unsigned short*)ws + OFF_W2P_US;
    bf16x8 a2[7][2];
    #pragma unroll
    for (int kd = 0; kd < 7; kd++)
        #pragma unroll
        for (int kk = 0; kk < 2; kk++)
            a2[kd][kk] = *(const bf16x8*)&w2p[(((wid * 7 + kd) * 2 + kk) * 64 + lane) * 8];

    for (int nt = 0; nt < 20; nt++) {
        int ar = nt >> 2, wbase = (nt & 3) * 16;
        fp32x4 acc = {0.f, 0.f, 0.f, 0.f};
        #pragma unroll
        for (int kd = 0; kd < 7; kd++) {
            int arp = ar + kd - 3;
            if (arp >= 0 && arp < 5) {   // uniform per (nt,kd)
                int sb = (arp * 64 + wbase + col) * 72;
                #pragma unroll
                for (int kk = 0; kk < 2; kk++) {
                    bf16x8 bf = *(const bf16x8*)&ol[sb + kk * 32 + quad * 8];
                    acc = __builtin_amdgcn_mfma_f32_16x16x32_bf16(a2[kd][kk], bf, acc, 0, 0, 0);
                }
            }
        }
        int w = wbase + col;
        #pragma unroll
        for (int r = 0; r < 4; r++) {
            int oc = wid * 16 + quad * 4 + r;
            out[((bu * 64 + oc) * 5 + ar) * 4096 + h * 64 + w] = fmaxf(acc[r], 0.f);
        }
    }
}

extern "C" void kernel_launch(void* const* d_in, const int* in_sizes, int n_in,
                              void* d_out, int out_size, void* d_ws, size_t ws_size,
                              hipStream_t stream) {
    const float* buf = (const float*)d_in[0];
    const float* Wq  = (const float*)d_in[1];
    const float* Wk  = (const float*)d_in[2];
    const float* Wv  = (const float*)d_in[3];
    const float* Wc  = (const float*)d_in[4];
    const float* W1  = (const float*)d_in[5];
    const float* W2  = (const float*)d_in[6];
    float* ws  = (float*)d_ws;
    float* out = (float*)d_out;

    prep_weights<<<208, 256, 0, stream>>>(Wq, Wk, Wv, Wc, W1, W2, ws);
    proj_kernel<<<2560, 256, 0, stream>>>(buf, ws);
    attn_kernel<<<2560, 256, 0, stream>>>(ws);
    conv12_mfma<<<512, 256, 0, stream>>>(ws, out);
}

// Round 9
// 166.142 us; speedup vs baseline: 1.0671x; 1.0038x over previous
//
#include <hip/hip_runtime.h>
#include <math.h>

// buffer [8,64,5,64,64] fp32; Wq/Wk [8,64]; Wv/Wc [40,64]; W1 [64,40,1,1,7]; W2 [64,64,7,1,1]
// out [8,64,5,64,64] fp32

typedef __attribute__((ext_vector_type(8))) short bf16x8;
typedef __attribute__((ext_vector_type(4))) short bf16x4;
typedef __attribute__((ext_vector_type(4))) float fp32x4;
typedef __attribute__((ext_vector_type(8))) unsigned short u16x8;

// ---- workspace layout ----
// float offsets:
#define OFF_WP      0         // [og=4][c=64][l=24] proj weights fp32            (6144 f)
#define OFF_Z       29696     // [bu=8][cz=40][ar=5][h=64][w=64] fp32            (6553600 f) end 6583296
// ushort offsets (us = (unsigned short*)ws):
#define OFF_W1P_US  12288     // [wid=4][ks=9][lane=64][8] bf16 A-frag pack      (18432 us)
#define OFF_W2P_US  30720     // [wid=4][kd=7][kk=2][lane=64][8] bf16            (28672 us) end us 59392 = f 29696
#define OFF_QFH_US  13166592  // [site=512][m=320][8] bf16                       (1310720 us)
#define OFF_KFH_US  14477312  // [site][n=320][8] bf16                           (1310720 us)
#define OFF_VTH_US  15788032  // [site][j=48][n=320] bf16 (j=40 ones)            (7864320 us) end us 23652352
// total ws = 11,826,176 floats = 47.3 MB

__device__ inline unsigned short f2b(float f) {   // RNE fp32 -> bf16
    unsigned u = __builtin_bit_cast(unsigned, f);
    u = (u + 0x7fffu + ((u >> 16) & 1u)) >> 16;
    return (unsigned short)u;
}

// 16x16x16 bf16 MFMA (legacy K=16 shape, retained on gfx950).
#if __has_builtin(__builtin_amdgcn_mfma_f32_16x16x16bf16_1k)
#define MFMA16(a, b, c) __builtin_amdgcn_mfma_f32_16x16x16bf16_1k(a, b, c, 0, 0, 0)
#else
static __device__ inline fp32x4 mfma16_asm(bf16x4 a, bf16x4 b, fp32x4 c) {
    asm("v_mfma_f32_16x16x16_bf16 %0, %1, %2, %0" : "+v"(c) : "v"(a), "v"(b));
    return c;
}
#define MFMA16(a, b, c) mfma16_asm(a, b, c)
#endif

// ---------------- kernel 0: weight shuffles / MFMA A-fragment packing ----------------
__global__ void prep_weights(const float* __restrict__ Wq, const float* __restrict__ Wk,
                             const float* __restrict__ Wv, const float* __restrict__ Wc,
                             const float* __restrict__ W1, const float* __restrict__ W2,
                             float* __restrict__ ws) {
    int e = blockIdx.x * 256 + threadIdx.x;
    unsigned short* us = (unsigned short*)ws;
    if (e < 6144) {
        int og = e / 1536, r = e % 1536;
        int c = r / 24, l = r % 24;
        int o = og * 24 + l;
        float v;
        if (o < 8)       v = Wq[o * 64 + c];
        else if (o < 16) v = Wk[(o - 8) * 64 + c];
        else if (o < 56) v = Wv[(o - 16) * 64 + c];
        else             v = Wc[(o - 56) * 64 + c];
        ws[OFF_WP + e] = v;
    } else if (e < 6144 + 18432) {
        // conv1 A pack: k = kw*40 + ic (K=280 padded to 288)
        int t = e - 6144;
        int j = t & 7, lane = (t >> 3) & 63, ks = (t >> 9) % 9, wid = t / 4608;
        int oc = wid * 16 + (lane & 15);
        int k = ks * 32 + (lane >> 4) * 8 + j;
        float v = 0.f;
        if (k < 280) { int kw = k / 40, ic = k % 40; v = W1[oc * 280 + ic * 7 + kw]; }
        us[OFF_W1P_US + t] = f2b(v);
    } else if (e < 6144 + 18432 + 28672) {
        // conv2 A pack: k = kd*64 + ic (K=448 exact)
        int t = e - 6144 - 18432;
        int j = t & 7, lane = (t >> 3) & 63, kk = (t >> 9) & 1, kd = (t >> 10) % 7, wid = t / 7168;
        int oc = wid * 16 + (lane & 15);
        int ic = kk * 32 + (lane >> 4) * 8 + j;
        us[OFF_W2P_US + t] = f2b(W2[oc * 448 + ic * 7 + kd]);
    }
}

// ---------------- kernel A: q/k/v/c projections (fused og, LDS-staged x) ----------------
// grid 2560 = (bu,v,h); 256 thr = 4 waves, wave = og. x-slab [c=64][w=64] fp32 staged to
// LDS once (coalesced float4). readfirstlane(og) keeps weight reads scalar.
__global__ __launch_bounds__(256) void proj_kernel(const float* __restrict__ buf,
                                                   float* __restrict__ ws) {
    __shared__ alignas(16) float xs[64 * 64];   // 16 KB
    int b = blockIdx.x;
    int h = b & 63;
    int v = (b >> 6) % 5;
    int bu = b / 320;
    int tid = threadIdx.x, wid = tid >> 6, w = tid & 63;

    // stage x[c][w] for this (bu,v,h): rows are 256B segments 80KB apart
    const float* xbase = buf + ((bu * 64) * 5 + v) * 4096 + h * 64;
    for (int e = tid; e < 1024; e += 256) {
        int c = e >> 4, wq = e & 15;
        *(float4*)&xs[c * 64 + wq * 4] = *(const float4*)&xbase[c * 20480 + wq * 4];
    }
    __syncthreads();

    int og = __builtin_amdgcn_readfirstlane(wid);
    const float* wp = ws + OFF_WP + og * 1536;

    float acc[24];
    #pragma unroll
    for (int l = 0; l < 24; l++) acc[l] = 0.f;
    for (int c = 0; c < 64; c++) {
        float x = xs[c * 64 + w];
        const float* wr = wp + c * 24;
        #pragma unroll
        for (int l = 0; l < 24; l++) acc[l] += wr[l] * x;
    }

    int site = bu * 64 + h;
    int n = v * 64 + w;
    unsigned short* base = (unsigned short*)ws;
    unsigned short* qfh = base + OFF_QFH_US;
    unsigned short* kfh = base + OFF_KFH_US;
    unsigned short* vth = base + OFF_VTH_US;
    float* z = ws + OFF_Z;

    if (og == 0) {
        u16x8 qv, kv;
        #pragma unroll
        for (int l = 0; l < 8; l++) { qv[l] = f2b(acc[l]); kv[l] = f2b(acc[8 + l]); }
        *(u16x8*)&qfh[(site * 320 + n) * 8] = qv;
        *(u16x8*)&kfh[(site * 320 + n) * 8] = kv;
        #pragma unroll
        for (int l = 16; l < 24; l++) vth[(site * 48 + (l - 16)) * 320 + n] = f2b(acc[l]);
    } else if (og == 1) {
        #pragma unroll
        for (int l = 0; l < 24; l++) vth[(site * 48 + 8 + l) * 320 + n] = f2b(acc[l]);
    } else if (og == 2) {
        #pragma unroll
        for (int l = 0; l < 8; l++) vth[(site * 48 + 32 + l) * 320 + n] = f2b(acc[l]);
        #pragma unroll
        for (int l = 8; l < 24; l++) {
            int j2 = l - 8;
            int c8 = j2 / 5, ar = j2 % 5;
            z[((bu * 40 + c8 * 5 + v) * 5 + ar) * 4096 + h * 64 + w] = acc[l];
        }
    } else {
        #pragma unroll
        for (int l = 0; l < 24; l++) {
            int j2 = 16 + l;
            int c8 = j2 / 5, ar = j2 % 5;
            z[((bu * 40 + c8 * 5 + v) * 5 + ar) * 4096 + h * 64 + w] = acc[l];
        }
        #pragma unroll
        for (int j = 40; j < 48; j++)
            vth[(site * 48 + j) * 320 + n] = (j == 40) ? (unsigned short)0x3F80 : (unsigned short)0;
    }
}

// ---------------- kernel B: attention, register-resident P, m-chunk split ----------------
// Swapped-operand QK: sT = mfma(K, Q) puts P[m=col][n=nt*16+quad*4+r] lane-local, which IS the
// 16x16x16 fragment layout -> exp + bf16-pack feeds PV directly from registers. PV computed as
// mfma(A=V^T, B=P) so out[j=quad*4+r][m=col]: coalesced z += epilogue, uniform 1/rowsum per lane.
// m-chunk split (grid 2560); z-RMW reads prefetched before QK (R7, -4.6us).
// R8 post-mortem: inline-asm v_cvt_pk_bf16_f32 broke numerics (inf: bad P -> rowsum L=0 ->
// 1/L=inf) -> reverted to the proven f2b integer pack at all sites.
// R9: K staged into LDS (5 KB) -- the 20 kb global loads per wave were issued inside the
// cc-loop and consumed by the first MFMA of each group (register pressure blocks full
// hoisting), exposing L2 latency on the QK critical path (same stall class R7's z-prefetch
// removed). kb mask dropped: qa is zero for k>=8, so A-operand content there is don't-care;
// unconditional LDS read is a same-address broadcast (conflict-free). Bit-identical.
__global__ __launch_bounds__(256, 2) void attn_kernel(float* __restrict__ ws) {
    __shared__ alignas(16) short vt[48 * 328];
    __shared__ alignas(16) short kl[320 * 8];   // 5 KB; total LDS 36.6 KB -> still 4 blocks/CU

    int bid = blockIdx.x;
    int chunk = bid >> 9;        // 0..4
    int site = bid & 511;
    int bu = site >> 6, h = site & 63;
    int tid = threadIdx.x;
    int wid = tid >> 6, lane = tid & 63;
    int col = lane & 15, quad = lane >> 4;

    const unsigned short* base = (const unsigned short*)ws;
    const unsigned short* qfh = base + OFF_QFH_US + site * 320 * 8;
    const unsigned short* kfh = base + OFF_KFH_US + site * 320 * 8;
    const unsigned short* vsrc = base + OFF_VTH_US + site * 48 * 320;
    float* z = ws + OFF_Z;

    for (int e = tid; e < 48 * 40; e += 256) {
        int row = e / 40, c8o = e % 40;
        *(u16x8*)&vt[row * 328 + c8o * 8] = *(const u16x8*)&vsrc[row * 320 + c8o * 8];
    }
    for (int e = tid; e < 320; e += 256)
        *(u16x8*)&kl[e * 8] = *(const u16x8*)&kfh[e * 8];
    __syncthreads();

    // epilogue channel offsets: j = jt*16 + quad*4 + r -> (c8*25 + ar)*4096, c8=j/5, ar=j%5
    int off0[4], off1[4], off2[4];
    #pragma unroll
    for (int r = 0; r < 4; r++) {
        int j0 = quad * 4 + r, j1 = j0 + 16, j2 = j0 + 32;
        off0[r] = ((j0 / 5) * 25 + j0 % 5) * 4096;
        off1[r] = ((j1 / 5) * 25 + j1 % 5) * 4096;
        off2[r] = ((j2 / 5) * 25 + j2 % 5) * 4096;
    }

    int mt = chunk * 4 + wid;    // this wave's m-tile (0..19)
    int m0 = mt * 16;

    // z-prefetch: addresses known now; loads drain while QK/softmax/PV runs
    int v_idx = m0 >> 6, w0 = m0 & 63;          // uniform per m-tile
    float* zb = z + (bu * 200 + v_idx * 5) * 4096 + h * 64 + w0 + col;
    float zold0[4], zold1[4], zold2[4];
    #pragma unroll
    for (int r = 0; r < 4; r++) {
        zold0[r] = zb[off0[r]];
        zold1[r] = zb[off1[r]];
        zold2[r] = (quad < 2) ? zb[off2[r]] : 0.f;
    }

    // Q^T as B operand: quad 0 holds ch 0..7 for column m = m0+col
    bf16x8 qa = (bf16x8)0;
    if (quad == 0) qa = *(const bf16x8*)&qfh[(m0 + col) * 8];

    fp32x4 acc0 = {0.f, 0.f, 0.f, 0.f}, acc1 = acc0, acc2 = acc0;

    for (int cc = 0; cc < 4; cc++) {
        fp32x4 sT[5];
        #pragma unroll
        for (int u = 0; u < 5; u++) {
            int nt = cc * 5 + u;
            // A operand: K rows n = nt*16+col from LDS; k>=8 slots are don't-care (qa==0 there)
            bf16x8 kb = *(const bf16x8*)&kl[(nt * 16 + col) * 8];
            sT[u] = __builtin_amdgcn_mfma_f32_16x16x32_bf16(
                kb, qa, (fp32x4){0.f, 0.f, 0.f, 0.f}, 0, 0, 0);
        }
        #pragma unroll
        for (int u = 0; u < 5; u++) {
            int nt = cc * 5 + u;
            bf16x4 pa;   // P[m=col][n = nt*16 + quad*4 + r] -> K=16 fragment
            #pragma unroll
            for (int r = 0; r < 4; r++) pa[r] = (short)f2b(__expf(sT[u][r]));
            const short* vb = &vt[nt * 16 + quad * 4];
            acc0 = MFMA16(*(const bf16x4*)&vb[(col) * 328],      pa, acc0);
            acc1 = MFMA16(*(const bf16x4*)&vb[(16 + col) * 328], pa, acc1);
            acc2 = MFMA16(*(const bf16x4*)&vb[(32 + col) * 328], pa, acc2);
        }
    }

    // rowsum L[m=col] sits at j=40 -> acc2[0] on quad==2 lanes
    float L = __shfl(acc2[0], 32 + col, 64);
    float inv = 1.f / L;

    #pragma unroll
    for (int r = 0; r < 4; r++) {
        zb[off0[r]] = zold0[r] + acc0[r] * inv;
        zb[off1[r]] = zold1[r] + acc1[r] * inv;
        if (quad < 2) zb[off2[r]] = zold2[r] + acc2[r] * inv;   // j = 32+quad*4+r < 40
    }
}

// ---------------- kernel C: fused conv1 (1,1,7) + conv2 (7,1,1) + ReLU via bf16 MFMA ----------------
// R4 structure. grid 512 = (bu,h); 256 thr. Phase 1 (conv1): per-ar z slab [wp=w+kw (72)][ic 40]
// bf16, double-buffered; conv1 bf16 results written straight to the ol slab. Phase 2 (conv2):
// reads ol from LDS. LDS 46080+11520 = 57.6 KB. (R8's cvt_pk reverted -> f2b.)
__global__ __launch_bounds__(256) void conv12_mfma(float* __restrict__ ws,
                                                   float* __restrict__ out) {
    __shared__ alignas(16) unsigned short ol[320 * 72];      // 46080 B
    __shared__ alignas(16) unsigned short zl2[2][72 * 40];   // 11520 B
    int b = blockIdx.x;
    int bu = b >> 6, h = b & 63;
    int tid = threadIdx.x, wid = tid >> 6, lane = tid & 63;
    int col = lane & 15, quad = lane >> 4;
    const float* z = ws + OFF_Z;

    const unsigned short* w1p = (const unsigned short*)ws + OFF_W1P_US;
    bf16x8 a1[9];
    #pragma unroll
    for (int ks = 0; ks < 9; ks++)
        a1[ks] = *(const bf16x8*)&w1p[((wid * 9 + ks) * 64 + lane) * 8];

    // stage one ar-slab of z into zl2[bufi]: halo zeros wp in {0,1,2,67..71}, interior wp=3+w
    #define STAGE_AR(ar_, bufi_)                                                          \
        {                                                                                 \
            unsigned short* zb_ = zl2[bufi_];                                             \
            if (tid < 160) {                                                              \
                int wpi = tid / 20, icd = tid % 20;                                       \
                int wp = wpi < 3 ? wpi : wpi + 64;                                        \
                ((unsigned*)zb_)[wp * 20 + icd] = 0u;                                     \
            }                                                                             \
            for (int icq = wid; icq < 10; icq += 4) {                                     \
                const float* src = z + ((bu * 40 + icq * 4) * 5 + (ar_)) * 4096 + h * 64 + lane; \
                ushort4 v4;                                                               \
                v4.x = f2b(src[0]);                                                       \
                v4.y = f2b(src[5 * 4096]);                                                \
                v4.z = f2b(src[10 * 4096]);                                               \
                v4.w = f2b(src[15 * 4096]);                                               \
                *(ushort4*)&zb_[(3 + lane) * 40 + icq * 4] = v4;                          \
            }                                                                             \
        }

    STAGE_AR(0, 0);
    __syncthreads();
    for (int ar = 0; ar < 5; ar++) {
        if (ar < 4) STAGE_AR(ar + 1, (ar + 1) & 1);   // prefetch into other buffer
        const unsigned short* zb = zl2[ar & 1];
        #pragma unroll
        for (int w4 = 0; w4 < 4; w4++) {
            int bb = (w4 * 16 + col) * 40;   // wp = w + kw, zl[wp] = z[wp-3]
            fp32x4 acc = {0.f, 0.f, 0.f, 0.f};
            #pragma unroll
            for (int ks = 0; ks < 9; ks++) {
                bf16x8 bf = *(const bf16x8*)&zb[bb + ks * 32 + quad * 8];
                acc = __builtin_amdgcn_mfma_f32_16x16x32_bf16(a1[ks], bf, acc, 0, 0, 0);
            }
            ushort4 o;
            o.x = f2b(fmaxf(acc[0], 0.f));
            o.y = f2b(fmaxf(acc[1], 0.f));
            o.z = f2b(fmaxf(acc[2], 0.f));
            o.w = f2b(fmaxf(acc[3], 0.f));
            *(ushort4*)&ol[(ar * 64 + w4 * 16 + col) * 72 + wid * 16 + quad * 4] = o;
        }
        __syncthreads();   // stage(ar+1) done; compute(ar) reads done before next overwrite
    }
    #undef STAGE_AR

    // ---- phase 2: conv2 over ar from ol ----
    const unsigned short* w2p = (const unsigned short*)ws + OFF_W2P_US;
    bf16x8 a2[7][2];
    #pragma unroll
    for (int kd = 0; kd < 7; kd++)
        #pragma unroll
        for (int kk = 0; kk < 2; kk++)
            a2[kd][kk] = *(const bf16x8*)&w2p[(((wid * 7 + kd) * 2 + kk) * 64 + lane) * 8];

    for (int nt = 0; nt < 20; nt++) {
        int ar = nt >> 2, wbase = (nt & 3) * 16;
        fp32x4 acc = {0.f, 0.f, 0.f, 0.f};
        #pragma unroll
        for (int kd = 0; kd < 7; kd++) {
            int arp = ar + kd - 3;
            if (arp >= 0 && arp < 5) {   // uniform per (nt,kd)
                int sb = (arp * 64 + wbase + col) * 72;
                #pragma unroll
                for (int kk = 0; kk < 2; kk++) {
                    bf16x8 bf = *(const bf16x8*)&ol[sb + kk * 32 + quad * 8];
                    acc = __builtin_amdgcn_mfma_f32_16x16x32_bf16(a2[kd][kk], bf, acc, 0, 0, 0);
                }
            }
        }
        int w = wbase + col;
        #pragma unroll
        for (int r = 0; r < 4; r++) {
            int oc = wid * 16 + quad * 4 + r;
            out[((bu * 64 + oc) * 5 + ar) * 4096 + h * 64 + w] = fmaxf(acc[r], 0.f);
        }
    }
}

extern "C" void kernel_launch(void* const* d_in, const int* in_sizes, int n_in,
                              void* d_out, int out_size, void* d_ws, size_t ws_size,
                              hipStream_t stream) {
    const float* buf = (const float*)d_in[0];
    const float* Wq  = (const float*)d_in[1];
    const float* Wk  = (const float*)d_in[2];
    const float* Wv  = (const float*)d_in[3];
    const float* Wc  = (const float*)d_in[4];
    const float* W1  = (const float*)d_in[5];
    const float* W2  = (const float*)d_in[6];
    float* ws  = (float*)d_ws;
    float* out = (float*)d_out;

    prep_weights<<<208, 256, 0, stream>>>(Wq, Wk, Wv, Wc, W1, W2, ws);
    proj_kernel<<<2560, 256, 0, stream>>>(buf, ws);
    attn_kernel<<<2560, 256, 0, stream>>>(ws);
    conv12_mfma<<<512, 256, 0, stream>>>(ws, out);
}